// Round 11
// baseline (92.554 us; speedup 1.0000x reference)
//
#include <hip/hip_runtime.h>
#include <hip/hip_bf16.h>
#include <stdint.h>

// Problem constants (fixed by the reference)
#define B_SZ 8192
#define D_SZ 256
#define R_SZ 8
#define N_SZ 1024
#define C_SZ (B_SZ / R_SZ)          // 1024
#define CN   (C_SZ * N_SZ)          // 1048576
#define L_SZ (B_SZ + 2 * R_SZ * CN) // 16785408 (logits length)
#define BD   (B_SZ * D_SZ)          // 2097152 elems per ws array

typedef short bf16x8 __attribute__((ext_vector_type(8)));
typedef float f32x4  __attribute__((ext_vector_type(4)));

static __device__ __forceinline__ unsigned short f2bf(float f) {
  unsigned u = __float_as_uint(f);
  u += 0x7FFFu + ((u >> 16) & 1u);   // RNE
  return (unsigned short)(u >> 16);
}
static __device__ __forceinline__ float bf2f(unsigned short h) {
  return __uint_as_float(((unsigned)h) << 16);
}
static __device__ __forceinline__ float sigmoidf_(float x) {
  return 1.0f / (1.0f + __expf(-x));
}

// ws layout (bytes), SORTED by relation (row p = r*1024 + c):
//   0    : lhs_hi_s (4MB)
//   4MB  : lhs_lo_s
//   8MB  : rhs_hi_s
//   12MB : rhs_lo_s
//   16MB : inv (32KB int)   inv[order[j]] = j

// ---------------------------------------------------------------------------
__global__ void inv_kernel(const int* __restrict__ order, int* __restrict__ inv) {
  int j = blockIdx.x * 256 + threadIdx.x;
  inv[order[j]] = j;
}

// ---------------------------------------------------------------------------
// Phase 1: F-reduce emb -> lhs/rhs, split bf16 hi+lo, SCATTER to sorted rows.
// One wave per batch row i. 2048 blocks x 256 threads. (~9 us, BW-bound.)
// ---------------------------------------------------------------------------
__global__ __launch_bounds__(256) void prep_kernel(
    const float* __restrict__ emb, const float* __restrict__ trans,
    const int* __restrict__ rels, const int* __restrict__ inv,
    float* __restrict__ out, unsigned short* __restrict__ sortArr) {
  unsigned short* lhs_hi = sortArr;
  unsigned short* lhs_lo = sortArr + (size_t)BD;
  unsigned short* rhs_hi = sortArr + (size_t)2 * BD;
  unsigned short* rhs_lo = sortArr + (size_t)3 * BD;

  int wave = threadIdx.x >> 6;
  int lane = threadIdx.x & 63;
  int i = blockIdx.x * 4 + wave;            // 0..B-1

  const float4* emb4 = (const float4*)emb;  // emb row j = 128 float4 (F*D=512 f32)
  size_t bl = (size_t)(2 * i) * 128;
  size_t br = (size_t)(2 * i + 1) * 128;
  float4 a0 = emb4[bl + lane];
  float4 a1 = emb4[bl + 64 + lane];
  float4 b0 = emb4[br + lane];
  float4 b1 = emb4[br + 64 + lane];
  float lh[4] = {a0.x + a1.x, a0.y + a1.y, a0.z + a1.z, a0.w + a1.w};
  float rh[4] = {b0.x + b1.x, b0.y + b1.y, b0.z + b1.z, b0.w + b1.w};

  int rel = rels[i];
  float4 tv = ((const float4*)trans)[rel * 64 + lane];
  float tt[4] = {tv.x, tv.y, tv.z, tv.w};

  float p = 0.f;
#pragma unroll
  for (int j = 0; j < 4; ++j) p += lh[j] * (rh[j] + tt[j]);
#pragma unroll
  for (int off = 32; off; off >>= 1) p += __shfl_xor(p, off, 64);
  if (lane == 0) {
    out[i] = p;
    out[(size_t)L_SZ + i] = sigmoidf_(p);
  }

  int sp = inv[i];  // sorted row
  unsigned short h[4], l[4];
#pragma unroll
  for (int j = 0; j < 4; ++j) {
    h[j] = f2bf(lh[j]);
    l[j] = f2bf(lh[j] - bf2f(h[j]));
  }
  *(ushort4*)(lhs_hi + (size_t)sp * 256 + lane * 4) = make_ushort4(h[0], h[1], h[2], h[3]);
  *(ushort4*)(lhs_lo + (size_t)sp * 256 + lane * 4) = make_ushort4(l[0], l[1], l[2], l[3]);
#pragma unroll
  for (int j = 0; j < 4; ++j) {
    h[j] = f2bf(rh[j]);
    l[j] = f2bf(rh[j] - bf2f(h[j]));
  }
  *(ushort4*)(rhs_hi + (size_t)sp * 256 + lane * 4) = make_ushort4(h[0], h[1], h[2], h[3]);
  *(ushort4*)(rhs_lo + (size_t)sp * 256 + lane * 4) = make_ushort4(l[0], l[1], l[2], l[3]);
}

// ---------------------------------------------------------------------------
// Phase 2: negatives GEMM with NO LDS and NO BARRIERS (operands are
// L2-resident: sorted ws + r==XCD swizzle -> 2MB slice per XCD).
// Each wave independently owns a 64x64 output tile and loads its MFMA
// fragments straight from global (16B/lane; lanes {l,l+16,l+32,l+48} cover a
// 64B row segment; wcol-sibling waves share A bytes via L1).
// 1024 blocks x 4 waves, ~150 VGPR, launch_bounds(256,3) -> 12 waves/CU,
// fully dephased: loads/MFMA/write-tails overlap across waves.
// Split-bf16: acc += Ah*Bh + Al*Bh + Ah*Bl (3 MFMA / frag pair).
// ---------------------------------------------------------------------------
__global__ __launch_bounds__(256, 3) void negs_kernel(
    const unsigned short* __restrict__ ws, const int* __restrict__ inv,
    const int* __restrict__ negL, const int* __restrict__ negR,
    float* __restrict__ out) {
  const char* base0 = (const char*)ws;

  int hw = blockIdx.x;
  int bid = (hw & 7) * 128 + (hw >> 3);   // bijective: r == XCD
  int ntile = bid & 7;
  int ctile = (bid >> 3) & 7;
  int side  = (bid >> 6) & 1;
  int r     = bid >> 7;

  int t = threadIdx.x;
  int wave = t >> 6, lane = t & 63;
  int wrow = wave >> 1, wcol = wave & 1;   // wave owns 64x64 at (wrow,wcol)
  int lx = lane & 15;
  int kq = lane >> 4;                      // k-quad 0..3 (8 bf16 = 16B each)

  // side 0: A = s_rhs, B = samp_lhs ; side 1: A = s_lhs, B = samp_rhs
  const char* aHi = base0 + (side ? 0 : ((size_t)8 << 20));
  const char* aLo = aHi + ((size_t)4 << 20);
  const char* bHi = base0 + (side ? ((size_t)8 << 20) : 0);
  const char* bLo = bHi + ((size_t)4 << 20);
  const int* negp = side ? negR : negL;

  // Per-lane fragment byte offsets (row*512 + kq*16); kt adds kt*64.
  unsigned aoff[4], boff[4];
  int arow0 = r * C_SZ + ctile * 128 + wrow * 64 + lx;
#pragma unroll
  for (int mi = 0; mi < 4; ++mi)
    aoff[mi] = (unsigned)(arow0 + mi * 16) * 512u + (unsigned)kq * 16u;
  int nb = r * N_SZ + ntile * 128 + wcol * 64 + lx;
#pragma unroll
  for (int ni = 0; ni < 4; ++ni)
    boff[ni] = (unsigned)inv[negp[nb + ni * 16]] * 512u + (unsigned)kq * 16u;

  f32x4 acc[4][4] = {};

#pragma unroll
  for (int kt = 0; kt < 8; ++kt) {
    unsigned kb = (unsigned)kt * 64u;
    bf16x8 ah[4], al_[4], bh[4], bl_[4];
#pragma unroll
    for (int mi = 0; mi < 4; ++mi) {
      ah[mi]  = *(const bf16x8*)(aHi + (aoff[mi] + kb));
      al_[mi] = *(const bf16x8*)(aLo + (aoff[mi] + kb));
    }
#pragma unroll
    for (int ni = 0; ni < 4; ++ni) {
      bh[ni]  = *(const bf16x8*)(bHi + (boff[ni] + kb));
      bl_[ni] = *(const bf16x8*)(bLo + (boff[ni] + kb));
    }
#pragma unroll
    for (int mi = 0; mi < 4; ++mi)
#pragma unroll
      for (int ni = 0; ni < 4; ++ni) {
        acc[mi][ni] = __builtin_amdgcn_mfma_f32_16x16x32_bf16(ah[mi],  bh[ni],  acc[mi][ni], 0, 0, 0);
        acc[mi][ni] = __builtin_amdgcn_mfma_f32_16x16x32_bf16(al_[mi], bh[ni],  acc[mi][ni], 0, 0, 0);
        acc[mi][ni] = __builtin_amdgcn_mfma_f32_16x16x32_bf16(ah[mi],  bl_[ni], acc[mi][ni], 0, 0, 0);
      }
  }

  // Epilogue: contiguous-row stores (proven). C/D: col = lane&15, row = (lane>>4)*4+jj.
  size_t obase = (size_t)B_SZ + (size_t)(r * 2 + side) * CN;
  int gcb = ntile * 128 + wcol * 64 + lx;
  int grb = ctile * 128 + wrow * 64 + (kq << 2);
#pragma unroll
  for (int mi = 0; mi < 4; ++mi) {
#pragma unroll
    for (int ni = 0; ni < 4; ++ni) {
      int gc = gcb + ni * 16;
#pragma unroll
      for (int jj = 0; jj < 4; ++jj) {
        int gr = grb + mi * 16 + jj;
        size_t idx = obase + (size_t)gr * N_SZ + gc;
        float v = acc[mi][ni][jj];
        out[idx] = v;
        out[(size_t)L_SZ + idx] = sigmoidf_(v);
      }
    }
  }
}

// ---------------------------------------------------------------------------
extern "C" void kernel_launch(void* const* d_in, const int* in_sizes, int n_in,
                              void* d_out, int out_size, void* d_ws, size_t ws_size,
                              hipStream_t stream) {
  const float* emb   = (const float*)d_in[0];
  const float* trans = (const float*)d_in[1];
  const int*   rels  = (const int*)d_in[2];
  const int*   order = (const int*)d_in[3];
  const int*   negL  = (const int*)d_in[4];
  const int*   negR  = (const int*)d_in[5];
  float* out = (float*)d_out;

  unsigned short* sortArr = (unsigned short*)d_ws;
  int* inv = (int*)((char*)d_ws + (size_t)16 * 1024 * 1024);

  inv_kernel<<<32, 256, 0, stream>>>(order, inv);
  prep_kernel<<<B_SZ / 4, 256, 0, stream>>>(emb, trans, rels, inv, out, sortArr);
  negs_kernel<<<1024, 256, 0, stream>>>(sortArr, inv, negL, negR, out);
}

// Round 12
// 50.660 us; speedup vs baseline: 1.8270x; 1.8270x over previous
//
#include <hip/hip_runtime.h>
#include <hip/hip_bf16.h>
#include <stdint.h>

// Problem constants (fixed by the reference)
#define B_SZ 8192
#define D_SZ 256
#define R_SZ 8
#define N_SZ 1024
#define C_SZ (B_SZ / R_SZ)          // 1024
#define CN   (C_SZ * N_SZ)          // 1048576
#define L_SZ (B_SZ + 2 * R_SZ * CN) // 16785408 (logits length)

// i8 fixed-point: round(v*1792) = 128*H + L, |H|<=127, |L|<=64.
#define FP_SCALE 1792.0f
#define FP_INV_S2 3.113918e-7f   // 1/(1792^2)

typedef int   i32x4 __attribute__((ext_vector_type(4)));
typedef float f32x4 __attribute__((ext_vector_type(4)));

static __device__ __forceinline__ float sigmoidf_(float x) {
  return 1.0f / (1.0f + __expf(-x));
}
static __device__ __forceinline__ void gload16(const void* g, void* l) {
  __builtin_amdgcn_global_load_lds(
      (const __attribute__((address_space(1))) void*)g,
      (__attribute__((address_space(3))) void*)l, 16, 0, 0);
}

// ws layout (bytes): 4 i8 arrays, row stride 256B (natural row order i):
//   0   : lhs_H (2MB)
//   2MB : lhs_L
//   4MB : rhs_H
//   6MB : rhs_L

// ---------------------------------------------------------------------------
// Phase 1: F-reduce emb -> lhs/rhs, quantize to i8 digit pairs, pos logits.
// One wave per batch row i. 2048 blocks x 256 threads. (~7.5 us, BW-bound.)
// ---------------------------------------------------------------------------
__global__ __launch_bounds__(256) void prep_kernel(
    const float* __restrict__ emb, const float* __restrict__ trans,
    const int* __restrict__ rels, float* __restrict__ out,
    char* __restrict__ ws) {
  char* lhs_H = ws;
  char* lhs_L = ws + ((size_t)2 << 20);
  char* rhs_H = ws + ((size_t)4 << 20);
  char* rhs_L = ws + ((size_t)6 << 20);

  int wave = threadIdx.x >> 6;
  int lane = threadIdx.x & 63;
  int i = blockIdx.x * 4 + wave;            // 0..B-1

  const float4* emb4 = (const float4*)emb;  // emb row j = 128 float4 (F*D=512 f32)
  size_t bl = (size_t)(2 * i) * 128;
  size_t br = (size_t)(2 * i + 1) * 128;
  float4 a0 = emb4[bl + lane];
  float4 a1 = emb4[bl + 64 + lane];
  float4 b0 = emb4[br + lane];
  float4 b1 = emb4[br + 64 + lane];
  float lh[4] = {a0.x + a1.x, a0.y + a1.y, a0.z + a1.z, a0.w + a1.w};
  float rh[4] = {b0.x + b1.x, b0.y + b1.y, b0.z + b1.z, b0.w + b1.w};

  int rel = rels[i];
  float4 tv = ((const float4*)trans)[rel * 64 + lane];
  float tt[4] = {tv.x, tv.y, tv.z, tv.w};

  float p = 0.f;
#pragma unroll
  for (int j = 0; j < 4; ++j) p += lh[j] * (rh[j] + tt[j]);
#pragma unroll
  for (int off = 32; off; off >>= 1) p += __shfl_xor(p, off, 64);
  if (lane == 0) {
    out[i] = p;
    out[(size_t)L_SZ + i] = sigmoidf_(p);
  }

  // Quantize: t = clamp(v*1792); H = rn(t/128); L = rn(t) - 128H  (|L|<=64)
  int phL = 0, plL = 0, phR = 0, plR = 0;
#pragma unroll
  for (int j = 0; j < 4; ++j) {
    float t = fminf(fmaxf(lh[j] * FP_SCALE, -16256.f), 16256.f);
    int hi = __float2int_rn(t * 0.0078125f);
    int lo = __float2int_rn(t) - (hi << 7);
    phL |= (hi & 255) << (8 * j);
    plL |= (lo & 255) << (8 * j);
    t = fminf(fmaxf(rh[j] * FP_SCALE, -16256.f), 16256.f);
    hi = __float2int_rn(t * 0.0078125f);
    lo = __float2int_rn(t) - (hi << 7);
    phR |= (hi & 255) << (8 * j);
    plR |= (lo & 255) << (8 * j);
  }
  size_t rowb = (size_t)i * 256 + lane * 4;
  *(int*)(lhs_H + rowb) = phL;
  *(int*)(lhs_L + rowb) = plL;
  *(int*)(rhs_H + rowb) = phR;
  *(int*)(rhs_L + rowb) = plR;
}

// ---------------------------------------------------------------------------
// Phase 2: gather-GEMM negatives, R1 skeleton with i8 numerics.
// 128x128 tile, 4 waves (2x2), BK=64 (i8: 64B rows), 4 K-chunks, single-buffer
// 32 KB LDS, proven 2-barrier schedule, 1024 blocks (2/CU).
// Wave w stages array w (A_H/A_L/B_H/B_L, 8KB each, 8x gload16 w=16).
// mfma_i32_16x16x64_i8: acc1 += Ha*Hb ; acc2 += La*Hb + Ha*Lb.
// logit = (16384*acc1 + 128*acc2) / 1792^2.
// XOR chunk swizzle: src chunk ^ ((row>>1)&3); read chunk q ^ ((row>>1)&3)
// -> 2-way max (free). Epilogue: contiguous-row plain stores (proven).
// ---------------------------------------------------------------------------
__global__ __launch_bounds__(256, 2) void negs_kernel(
    const char* __restrict__ ws,
    const int* __restrict__ order,
    const int* __restrict__ negL, const int* __restrict__ negR,
    float* __restrict__ out) {
  __shared__ char lds[4][8192];  // A_H, A_L, B_H, B_L ; 128 rows x 64B

  const char* lhs_H = ws;
  const char* lhs_L = ws + ((size_t)2 << 20);
  const char* rhs_H = ws + ((size_t)4 << 20);
  const char* rhs_L = ws + ((size_t)6 << 20);

  int bid = blockIdx.x;
  int ntile = bid & 7;
  int ctile = (bid >> 3) & 7;
  int side  = (bid >> 6) & 1;
  int r     = bid >> 7;

  int wave = threadIdx.x >> 6;
  int lane = threadIdx.x & 63;
  int wrow = wave >> 1, wcol = wave & 1;
  int lx = lane & 15;

  // side 0: A = s_rhs, B = samp_lhs ; side 1: A = s_lhs, B = samp_rhs
  const char* srcp;
  const int* idxp;
  int idxbase;
  if (wave < 2) {
    idxp = order;
    idxbase = r * C_SZ + ctile * 128;
    srcp = (wave == 0) ? (side ? lhs_H : rhs_H) : (side ? lhs_L : rhs_L);
  } else {
    idxp = side ? negR : negL;
    idxbase = r * N_SZ + ntile * 128;
    srcp = (wave == 2) ? (side ? rhs_H : lhs_H) : (side ? rhs_L : lhs_L);
  }

  // Staging map: load 'it' covers LDS rows it*16 + (lane>>2), chunk lane&3.
  // Source chunk inverse-swizzled: (lane&3) ^ ((row>>1)&3) = (lane&3)^((lane>>3)&3).
  unsigned srcswz = (unsigned)(((lane & 3) ^ ((lane >> 3) & 3)) << 4);
  unsigned goff[8];
#pragma unroll
  for (int it = 0; it < 8; ++it) {
    int grow = idxp[idxbase + it * 16 + (lane >> 2)];
    goff[it] = (unsigned)grow * 256u + srcswz;
  }
  char* myLds = &lds[wave][0];

  i32x4 acc1[4][4] = {};  // Ha*Hb
  i32x4 acc2[4][4] = {};  // La*Hb + Ha*Lb
  int q = lane >> 4;      // logical 16B chunk 0..3 within 64B row

#pragma unroll 1
  for (int kc = 0; kc < 4; ++kc) {
#pragma unroll
    for (int it = 0; it < 8; ++it)
      gload16(srcp + goff[it] + (unsigned)kc * 64u, myLds + it * 1024);
    __syncthreads();

    i32x4 ha[4], la[4], hb[4], lb[4];
#pragma unroll
    for (int mi = 0; mi < 4; ++mi) {
      int row = wrow * 64 + mi * 16 + lx;
      int off = row * 64 + ((q ^ ((row >> 1) & 3)) << 4);
      ha[mi] = *(const i32x4*)(&lds[0][0] + off);
      la[mi] = *(const i32x4*)(&lds[1][0] + off);
    }
#pragma unroll
    for (int ni = 0; ni < 4; ++ni) {
      int row = wcol * 64 + ni * 16 + lx;
      int off = row * 64 + ((q ^ ((row >> 1) & 3)) << 4);
      hb[ni] = *(const i32x4*)(&lds[2][0] + off);
      lb[ni] = *(const i32x4*)(&lds[3][0] + off);
    }
#pragma unroll
    for (int mi = 0; mi < 4; ++mi)
#pragma unroll
      for (int ni = 0; ni < 4; ++ni) {
        acc1[mi][ni] = __builtin_amdgcn_mfma_i32_16x16x64_i8(ha[mi], hb[ni], acc1[mi][ni], 0, 0, 0);
        acc2[mi][ni] = __builtin_amdgcn_mfma_i32_16x16x64_i8(la[mi], hb[ni], acc2[mi][ni], 0, 0, 0);
        acc2[mi][ni] = __builtin_amdgcn_mfma_i32_16x16x64_i8(ha[mi], lb[ni], acc2[mi][ni], 0, 0, 0);
      }
    __syncthreads();
  }

  // Epilogue: contiguous-row stores. C/D layout col = lane&15, row = (lane>>4)*4+jj.
  size_t obase = (size_t)B_SZ + ((size_t)(r * 2 + side)) * CN;
  int gcb = ntile * 128 + wcol * 64 + lx;
  int grb = ctile * 128 + wrow * 64 + ((lane >> 4) << 2);
#pragma unroll
  for (int mi = 0; mi < 4; ++mi) {
#pragma unroll
    for (int ni = 0; ni < 4; ++ni) {
      int gc = gcb + ni * 16;
#pragma unroll
      for (int jj = 0; jj < 4; ++jj) {
        int gr = grb + mi * 16 + jj;
        size_t idx = obase + (size_t)gr * N_SZ + gc;
        float v = fmaf(16384.0f, (float)acc1[mi][ni][jj],
                       128.0f * (float)acc2[mi][ni][jj]) * FP_INV_S2;
        out[idx] = v;
        out[(size_t)L_SZ + idx] = sigmoidf_(v);
      }
    }
  }
}

// ---------------------------------------------------------------------------
extern "C" void kernel_launch(void* const* d_in, const int* in_sizes, int n_in,
                              void* d_out, int out_size, void* d_ws, size_t ws_size,
                              hipStream_t stream) {
  const float* emb   = (const float*)d_in[0];
  const float* trans = (const float*)d_in[1];
  const int*   rels  = (const int*)d_in[2];
  const int*   order = (const int*)d_in[3];
  const int*   negL  = (const int*)d_in[4];
  const int*   negR  = (const int*)d_in[5];
  float* out = (float*)d_out;
  char* ws = (char*)d_ws;  // 8 MB of i8 digit arrays

  prep_kernel<<<B_SZ / 4, 256, 0, stream>>>(emb, trans, rels, out, ws);
  negs_kernel<<<R_SZ * 2 * 8 * 8, 256, 0, stream>>>(ws, order, negL, negR, out);
}